// Round 15
// baseline (416.938 us; speedup 1.0000x reference)
//
#include <hip/hip_runtime.h>
#include <hip/hip_bf16.h>
#include <math.h>

#define B 64
#define L 2048
#define C 1024          // D_K = D_Q
#define NH 8
#define DK 128
#define SCALE 0.08838834764831845f   // 1/sqrt(128)

// DPP helper: dst = dpp_perm(src) per CTRL; masked-off/invalid lanes yield 0.
template<int CTRL, int RMASK = 0xF>
__device__ __forceinline__ float dppmov(float x) {
    return __int_as_float(__builtin_amdgcn_update_dpp(
        0, __float_as_int(x), CTRL, RMASK, 0xF, true));
}
// Full wave64 sum via DPP; result in LANE 63.
__device__ __forceinline__ float wave_sum_dpp(float s) {
    s += dppmov<0x111>(s);          // row_shr:1
    s += dppmov<0x112>(s);          // row_shr:2
    s += dppmov<0x114>(s);          // row_shr:4
    s += dppmov<0x118>(s);          // row_shr:8
    s += dppmov<0x142, 0xa>(s);     // row_bcast:15 into rows 1,3
    s += dppmov<0x143, 0xc>(s);     // row_bcast:31 into rows 2,3 -> lane63 total
    return s;
}

// ---------------------------------------------------------------------------
// k_qs: qs[b, j] = bias[j] + sum_c q[b,c] * wq[j,c]   (64 x 1024)
__global__ void k_qs(const float* __restrict__ q, const float* __restrict__ wq,
                     const float* __restrict__ bq, float* __restrict__ qs) {
    int t = threadIdx.x, w = t >> 6, lane = t & 63;
    int j = blockIdx.x * 4 + w;
    float4 W[4];
#pragma unroll
    for (int kk = 0; kk < 4; kk++)
        W[kk] = *(const float4*)&wq[(size_t)j * C + kk * 256 + lane * 4];
    float bj = bq[j];
    for (int b = 0; b < B; b++) {
        float s = 0.f;
#pragma unroll
        for (int kk = 0; kk < 4; kk++) {
            float4 qv = *(const float4*)&q[(size_t)b * C + kk * 256 + lane * 4];
            s += W[kk].x * qv.x + W[kk].y * qv.y + W[kk].z * qv.z + W[kk].w * qv.w;
        }
        s = wave_sum_dpp(s);
        if (lane == 63) qs[(size_t)b * C + j] = s + bj;
    }
}

// ---------------------------------------------------------------------------
// k_qtilde: qtilde[b,n,c] = SCALE * sum_d qs[b, n*128+d] * wk[n*128+d, c]
__global__ void k_qtilde(const float* __restrict__ qs, const float* __restrict__ wk,
                         float* __restrict__ qtilde) {
    int n = blockIdx.x >> 2, cc = blockIdx.x & 3, bg = blockIdx.y;
    int t = threadIdx.x;
    int c = cc * 256 + t;
    __shared__ float qss[8][128];
    for (int p = 0; p < 4; p++) {
        int e = p * 256 + t;
        int i = e >> 7, d = e & 127;
        qss[i][d] = qs[(size_t)(bg * 8 + i) * C + n * DK + d];
    }
    __syncthreads();
    float acc[8];
#pragma unroll
    for (int i = 0; i < 8; i++) acc[i] = 0.f;
    for (int d = 0; d < DK; d += 4) {
        float wv0 = wk[(size_t)(n * DK + d + 0) * C + c];
        float wv1 = wk[(size_t)(n * DK + d + 1) * C + c];
        float wv2 = wk[(size_t)(n * DK + d + 2) * C + c];
        float wv3 = wk[(size_t)(n * DK + d + 3) * C + c];
#pragma unroll
        for (int i = 0; i < 8; i++) {
            acc[i] += qss[i][d + 0] * wv0 + qss[i][d + 1] * wv1
                    + qss[i][d + 2] * wv2 + qss[i][d + 3] * wv3;
        }
    }
#pragma unroll
    for (int i = 0; i < 8; i++)
        qtilde[((size_t)(bg * 8 + i) * NH + n) * C + c] = acc[i] * SCALE;
}

// ---------------------------------------------------------------------------
// k_fused10: round-13 fused8 with PAIR-STEP dist-2 prefetch: compute pair p
// from its buffer, THEN reload that buffer with pair p+2 -> load lead time =
// one full pair of compute (~1120 cyc) > HBM latency (~900 cyc). Two pair
// buffers (kA, kB), all statically indexed. DPP reduce; no main-loop barrier.
__global__ __launch_bounds__(512, 2) void k_fused10(
    const float* __restrict__ kmat, const float* __restrict__ qtilde,
    const unsigned char* __restrict__ mask,
    float* __restrict__ pout,             // (n*B + b)*L + l : exp(score)
    float* __restrict__ accpart,          // [b][lp4][n][C]
    float* __restrict__ zpart) {          // [b][lp4][n]
    const int b = blockIdx.x, lp = blockIdx.y;
    const int t = threadIdx.x, w = t >> 6, lane = t & 63;
    const int chunk = w >> 1;            // 0..3 (128 rows each)
    const int hg = w & 1;                // 0..1 (heads hg*4..hg*4+3)
    const int l0 = lp * 512 + chunk * 128;
    const int hl = lane & 3;

    __shared__ float ctxl[NH * C];       // 32 KB
    __shared__ float zl[NH];

    float4 qt[4][4];
#pragma unroll
    for (int j = 0; j < 4; j++)
#pragma unroll
        for (int kk = 0; kk < 4; kk++)
            qt[j][kk] = *(const float4*)&qtilde[((size_t)b * NH + hg * 4 + j) * C + kk * 256 + lane * 4];

    float4 acc[4][4];
#pragma unroll
    for (int j = 0; j < 4; j++)
#pragma unroll
        for (int kk = 0; kk < 4; kk++) acc[j][kk] = make_float4(0.f, 0.f, 0.f, 0.f);
    float zacc = 0.f;

    const float* kp = kmat + ((size_t)b * L + l0) * C + lane * 4;
    const unsigned char* mp = mask + (size_t)b * L + l0;

    // one-row compute: dots -> DPP butterfly -> exp -> z/ss -> ctx FMA
    auto ROW = [&](const float4 (&kq4)[4], unsigned char mk, float& ssl) {
        float s0 = 0.f, s1 = 0.f, s2 = 0.f, s3 = 0.f;
#pragma unroll
        for (int kk = 0; kk < 4; kk++) {
            float4 kq = kq4[kk];
            s0 += qt[0][kk].x * kq.x + qt[0][kk].y * kq.y + qt[0][kk].z * kq.z + qt[0][kk].w * kq.w;
            s1 += qt[1][kk].x * kq.x + qt[1][kk].y * kq.y + qt[1][kk].z * kq.z + qt[1][kk].w * kq.w;
            s2 += qt[2][kk].x * kq.x + qt[2][kk].y * kq.y + qt[2][kk].z * kq.z + qt[2][kk].w * kq.w;
            s3 += qt[3][kk].x * kq.x + qt[3][kk].y * kq.y + qt[3][kk].z * kq.z + qt[3][kk].w * kq.w;
        }
        float a01 = (lane & 1) ? s1 : s0;
        float g01 = (lane & 1) ? s0 : s1;
        float a23 = (lane & 1) ? s3 : s2;
        float g23 = (lane & 1) ? s2 : s3;
        float u  = a01 + dppmov<0xB1>(g01);        // quad_perm xor1
        float v2 = a23 + dppmov<0xB1>(g23);
        float keep = (lane & 2) ? v2 : u;
        float give = (lane & 2) ? u : v2;
        float v = keep + dppmov<0x4E>(give);       // quad_perm xor2
        v += dppmov<0x124>(v);                     // row_ror:4
        v += dppmov<0x128>(v);                     // row_ror:8
        v += __int_as_float(__builtin_amdgcn_ds_swizzle(
                 __float_as_int(v), 0x401F));      // xor16 (within 32-half)
        v += __shfl_xor(v, 32, 64);                // cross-32
        float p = __expf(mk ? -INFINITY : v);
        zacc += p;                                 // p = FULL row sum for head (lane&3)
        ssl = p;
        float p1 = dppmov<0xB1>(p);
        float p2 = dppmov<0x4E>(p);
        float p3 = dppmov<0x4E>(p1);
#pragma unroll
        for (int kk = 0; kk < 4; kk++) {
            float4 kq = kq4[kk];
            acc[0][kk].x += p  * kq.x; acc[0][kk].y += p  * kq.y; acc[0][kk].z += p  * kq.z; acc[0][kk].w += p  * kq.w;
            acc[1][kk].x += p1 * kq.x; acc[1][kk].y += p1 * kq.y; acc[1][kk].z += p1 * kq.z; acc[1][kk].w += p1 * kq.w;
            acc[2][kk].x += p2 * kq.x; acc[2][kk].y += p2 * kq.y; acc[2][kk].z += p2 * kq.z; acc[2][kk].w += p2 * kq.w;
            acc[3][kk].x += p3 * kq.x; acc[3][kk].y += p3 * kq.y; acc[3][kk].z += p3 * kq.z; acc[3][kk].w += p3 * kq.w;
        }
    };

    // prologue: pairs 0 (rows 0,1) -> kA, 1 (rows 2,3) -> kB
    float4 kA[2][4], kB[2][4];
#pragma unroll
    for (int kk = 0; kk < 4; kk++) {
        kA[0][kk] = *(const float4*)(kp + 0 * C + kk * 256);
        kA[1][kk] = *(const float4*)(kp + 1 * C + kk * 256);
        kB[0][kk] = *(const float4*)(kp + 2 * C + kk * 256);
        kB[1][kk] = *(const float4*)(kp + 3 * C + kk * 256);
    }

    for (int rb = 0; rb < 32; rb++) {
        uchar4 mb = *(const uchar4*)&mp[rb * 4];
        float ss[4];
        // even pair: rows 4rb, 4rb+1 from kA; then reload kA with rows +4,+5
        ROW(kA[0], mb.x, ss[0]);
        ROW(kA[1], mb.y, ss[1]);
        if (rb < 31) {
            const float* np = kp + (size_t)(rb * 4 + 4) * C;
#pragma unroll
            for (int kk = 0; kk < 4; kk++) {
                kA[0][kk] = *(const float4*)(np + kk * 256);
                kA[1][kk] = *(const float4*)(np + C + kk * 256);
            }
        }
        // odd pair: rows 4rb+2, 4rb+3 from kB; then reload kB with rows +6,+7
        ROW(kB[0], mb.z, ss[2]);
        ROW(kB[1], mb.w, ss[3]);
        if (rb < 31) {
            const float* np = kp + (size_t)(rb * 4 + 6) * C;
#pragma unroll
            for (int kk = 0; kk < 4; kk++) {
                kB[0][kk] = *(const float4*)(np + kk * 256);
                kB[1][kk] = *(const float4*)(np + C + kk * 256);
            }
        }
        if (lane < 4) {
            float4 o = make_float4(ss[0], ss[1], ss[2], ss[3]);
            *(float4*)&pout[((size_t)(hg * 4 + lane) * B + b) * L + l0 + rb * 4] = o;
        }
    }

    // phased LDS merge across chunks; un-permute head mapping h = hg*4+(hl^j)
    __syncthreads();
    for (int ph = 0; ph < 4; ph++) {
        if (chunk == ph) {
#pragma unroll
            for (int j = 0; j < 4; j++) {
                int h = hg * 4 + (hl ^ j);
                float* dst = &ctxl[(size_t)h * C + lane * 4];
                if (ph == 0) {
#pragma unroll
                    for (int kk = 0; kk < 4; kk++)
                        *(float4*)&dst[kk * 256] = acc[j][kk];
                } else {
#pragma unroll
                    for (int kk = 0; kk < 4; kk++) {
                        float4 o = *(const float4*)&dst[kk * 256];
                        float4 a = acc[j][kk];
                        o.x += a.x; o.y += a.y; o.z += a.z; o.w += a.w;
                        *(float4*)&dst[kk * 256] = o;
                    }
                }
            }
            if (lane < 4) {
                if (ph == 0) zl[hg * 4 + lane] = zacc;
                else         zl[hg * 4 + lane] += zacc;
            }
        }
        __syncthreads();
    }
    float* ap = accpart + ((size_t)b * 4 + lp) * (NH * C);
#pragma unroll
    for (int i = 0; i < 4; i++) {
        int idx = t * 16 + i * 4;
        *(float4*)&ap[idx] = *(const float4*)&ctxl[idx];
    }
    if (t < NH) zpart[((size_t)b * 4 + lp) * NH + t] = zl[t];
}

// ---------------------------------------------------------------------------
// k_combine2: ctx[b,n,c] = (sum_lp accpart) / Z; ALSO scales pout by Zinv.
__global__ void k_combine2(const float* __restrict__ accpart, const float* __restrict__ zpart,
                           float* __restrict__ ctx, float* __restrict__ pout) {
    int b = blockIdx.x, cq = blockIdx.y;
    int t = threadIdx.x;
    int c = cq * 256 + t;
    __shared__ float zi[NH];
    if (t < NH) {
        float z = 0.f;
#pragma unroll
        for (int lpp = 0; lpp < 4; lpp++) z += zpart[((size_t)b * 4 + lpp) * NH + t];
        zi[t] = 1.0f / z;
    }
    __syncthreads();
#pragma unroll
    for (int n = 0; n < NH; n++) {
        float s = 0.f;
#pragma unroll
        for (int lpp = 0; lpp < 4; lpp++)
            s += accpart[(((size_t)b * 4 + lpp) * NH + n) * C + c];
        ctx[((size_t)b * NH + n) * C + c] = s * zi[n];
    }
#pragma unroll
    for (int n = 0; n < NH; n++) {
        float zin = zi[n];
        float2* pp = (float2*)&pout[((size_t)n * B + b) * L + cq * 512];
        float2 v = pp[t];
        v.x *= zin; v.y *= zin;
        pp[t] = v;
    }
}

// ---------------------------------------------------------------------------
// k_out: output[b, j] = bv[j] + sum_c wv[j,c] * ctx[b, n(j), c]
__global__ void k_out(const float* __restrict__ ctx, const float* __restrict__ wv,
                      const float* __restrict__ bv, float* __restrict__ out) {
    int t = threadIdx.x, w = t >> 6, lane = t & 63;
    int j = blockIdx.x * 4 + w;
    int n = j >> 7;
    float4 W[4];
#pragma unroll
    for (int kk = 0; kk < 4; kk++)
        W[kk] = *(const float4*)&wv[(size_t)j * C + kk * 256 + lane * 4];
    float bj = bv[j];
    for (int b = 0; b < B; b++) {
        float s = 0.f;
#pragma unroll
        for (int kk = 0; kk < 4; kk++) {
            float4 cv = *(const float4*)&ctx[((size_t)b * NH + n) * C + kk * 256 + lane * 4];
            s += W[kk].x * cv.x + W[kk].y * cv.y + W[kk].z * cv.z + W[kk].w * cv.w;
        }
        s = wave_sum_dpp(s);
        if (lane == 63) out[(size_t)b * (NH * DK) + j] = s + bj;
    }
}

// ---------------------------------------------------------------------------
extern "C" void kernel_launch(void* const* d_in, const int* in_sizes, int n_in,
                              void* d_out, int out_size, void* d_ws, size_t ws_size,
                              hipStream_t stream) {
    const float* q    = (const float*)d_in[0];
    const float* kmat = (const float*)d_in[1];
    const unsigned char* mask = (const unsigned char*)d_in[2];
    const float* wq = (const float*)d_in[3];
    const float* bq = (const float*)d_in[4];
    const float* wk = (const float*)d_in[5];
    // d_in[6] = w_ks_b: softmax-invariant -> unused.
    const float* wv = (const float*)d_in[7];
    const float* bv = (const float*)d_in[8];

    float* out  = (float*)d_out;            // (64, 1024)
    float* attn = out + B * NH * DK;        // (8*64, 2048): exp(s) -> scaled

    float* ws      = (float*)d_ws;
    float* qs      = ws;                     // 65536 floats (dead after k_qtilde)
    float* zpart   = ws;                     // 2048 floats overlay (64*4*8)
    float* qtilde  = ws + 65536;             // 524288 floats, reused as ctx
    float* ctx     = qtilde;
    float* accpart = ws + 65536 + 524288;    // 2097152 floats

    hipLaunchKernelGGL(k_qs, dim3(256), dim3(256), 0, stream, q, wq, bq, qs);
    hipLaunchKernelGGL(k_qtilde, dim3(32, 8), dim3(256), 0, stream, qs, wk, qtilde);
    hipLaunchKernelGGL(k_fused10, dim3(64, 4), dim3(512), 0, stream,
                       kmat, qtilde, mask, attn, accpart, zpart);
    hipLaunchKernelGGL(k_combine2, dim3(64, 4), dim3(256), 0, stream,
                       accpart, zpart, ctx, attn);
    hipLaunchKernelGGL(k_out, dim3(256), dim3(256), 0, stream, ctx, wv, bv, out);
}

// Round 16
// 233.514 us; speedup vs baseline: 1.7855x; 1.7855x over previous
//
#include <hip/hip_runtime.h>
#include <hip/hip_bf16.h>
#include <math.h>

#define B 64
#define L 2048
#define C 1024          // D_K = D_Q
#define NH 8
#define DK 128
#define SCALE 0.08838834764831845f   // 1/sqrt(128)

// DPP helper: dst = dpp_perm(src) per CTRL; masked-off/invalid lanes yield 0.
template<int CTRL, int RMASK = 0xF>
__device__ __forceinline__ float dppmov(float x) {
    return __int_as_float(__builtin_amdgcn_update_dpp(
        0, __float_as_int(x), CTRL, RMASK, 0xF, true));
}
// Full wave64 sum via DPP; result in LANE 63.
__device__ __forceinline__ float wave_sum_dpp(float s) {
    s += dppmov<0x111>(s);          // row_shr:1
    s += dppmov<0x112>(s);          // row_shr:2
    s += dppmov<0x114>(s);          // row_shr:4
    s += dppmov<0x118>(s);          // row_shr:8
    s += dppmov<0x142, 0xa>(s);     // row_bcast:15 into rows 1,3
    s += dppmov<0x143, 0xc>(s);     // row_bcast:31 into rows 2,3 -> lane63 total
    return s;
}

// ---------------------------------------------------------------------------
// k_qs: qs[b, j] = bias[j] + sum_c q[b,c] * wq[j,c]   (64 x 1024)
__global__ void k_qs(const float* __restrict__ q, const float* __restrict__ wq,
                     const float* __restrict__ bq, float* __restrict__ qs) {
    int t = threadIdx.x, w = t >> 6, lane = t & 63;
    int j = blockIdx.x * 4 + w;
    float4 W[4];
#pragma unroll
    for (int kk = 0; kk < 4; kk++)
        W[kk] = *(const float4*)&wq[(size_t)j * C + kk * 256 + lane * 4];
    float bj = bq[j];
    for (int b = 0; b < B; b++) {
        float s = 0.f;
#pragma unroll
        for (int kk = 0; kk < 4; kk++) {
            float4 qv = *(const float4*)&q[(size_t)b * C + kk * 256 + lane * 4];
            s += W[kk].x * qv.x + W[kk].y * qv.y + W[kk].z * qv.z + W[kk].w * qv.w;
        }
        s = wave_sum_dpp(s);
        if (lane == 63) qs[(size_t)b * C + j] = s + bj;
    }
}

// ---------------------------------------------------------------------------
// k_qtilde: qtilde[b,n,c] = SCALE * sum_d qs[b, n*128+d] * wk[n*128+d, c]
__global__ void k_qtilde(const float* __restrict__ qs, const float* __restrict__ wk,
                         float* __restrict__ qtilde) {
    int n = blockIdx.x >> 2, cc = blockIdx.x & 3, bg = blockIdx.y;
    int t = threadIdx.x;
    int c = cc * 256 + t;
    __shared__ float qss[8][128];
    for (int p = 0; p < 4; p++) {
        int e = p * 256 + t;
        int i = e >> 7, d = e & 127;
        qss[i][d] = qs[(size_t)(bg * 8 + i) * C + n * DK + d];
    }
    __syncthreads();
    float acc[8];
#pragma unroll
    for (int i = 0; i < 8; i++) acc[i] = 0.f;
    for (int d = 0; d < DK; d += 4) {
        float wv0 = wk[(size_t)(n * DK + d + 0) * C + c];
        float wv1 = wk[(size_t)(n * DK + d + 1) * C + c];
        float wv2 = wk[(size_t)(n * DK + d + 2) * C + c];
        float wv3 = wk[(size_t)(n * DK + d + 3) * C + c];
#pragma unroll
        for (int i = 0; i < 8; i++) {
            acc[i] += qss[i][d + 0] * wv0 + qss[i][d + 1] * wv1
                    + qss[i][d + 2] * wv2 + qss[i][d + 3] * wv3;
        }
    }
#pragma unroll
    for (int i = 0; i < 8; i++)
        qtilde[((size_t)(bg * 8 + i) * NH + n) * C + c] = acc[i] * SCALE;
}

// ---------------------------------------------------------------------------
// k_fused8b: round-13 fused8 per-wave code UNCHANGED; grid split lp 4->8
// (512 blocks, 64 rows/chunk) so 2 blocks co-reside per CU -> 4 waves/SIMD
// of TLP latency hiding with the same ~105-VGPR spill-free footprint.
__global__ __launch_bounds__(512, 2) void k_fused8b(
    const float* __restrict__ kmat, const float* __restrict__ qtilde,
    const unsigned char* __restrict__ mask,
    float* __restrict__ pout,             // (n*B + b)*L + l : exp(score)
    float* __restrict__ accpart,          // [b][lp8][n][C]
    float* __restrict__ zpart) {          // [b][lp8][n]
    const int b = blockIdx.x, lp = blockIdx.y;
    const int t = threadIdx.x, w = t >> 6, lane = t & 63;
    const int chunk = w >> 1;            // 0..3 (64 rows each)
    const int hg = w & 1;                // 0..1 (heads hg*4..hg*4+3)
    const int l0 = lp * 256 + chunk * 64;
    const int hl = lane & 3;

    __shared__ float ctxl[NH * C];       // 32 KB
    __shared__ float zl[NH];

    float4 qt[4][4];
#pragma unroll
    for (int j = 0; j < 4; j++)
#pragma unroll
        for (int kk = 0; kk < 4; kk++)
            qt[j][kk] = *(const float4*)&qtilde[((size_t)b * NH + hg * 4 + j) * C + kk * 256 + lane * 4];

    float4 acc[4][4];
#pragma unroll
    for (int j = 0; j < 4; j++)
#pragma unroll
        for (int kk = 0; kk < 4; kk++) acc[j][kk] = make_float4(0.f, 0.f, 0.f, 0.f);
    float zacc = 0.f;

    const float* kp = kmat + ((size_t)b * L + l0) * C + lane * 4;
    const unsigned char* mp = mask + (size_t)b * L + l0;

    float4 kv[2][4];
#pragma unroll
    for (int kk = 0; kk < 4; kk++) kv[0][kk] = *(const float4*)(kp + kk * 256);

    for (int rb = 0; rb < 16; rb++) {
        uchar4 mb = *(const uchar4*)&mp[rb * 4];
        float ss[4];
#pragma unroll
        for (int rr = 0; rr < 4; rr++) {
            const int r = rb * 4 + rr;
            const int cur = r & 1;
            if (r < 63) {
                const float* np = kp + (size_t)(r + 1) * C;
#pragma unroll
                for (int kk = 0; kk < 4; kk++)
                    kv[cur ^ 1][kk] = *(const float4*)(np + kk * 256);
            }
            float s0 = 0.f, s1 = 0.f, s2 = 0.f, s3 = 0.f;
#pragma unroll
            for (int kk = 0; kk < 4; kk++) {
                float4 kq = kv[cur][kk];
                s0 += qt[0][kk].x * kq.x + qt[0][kk].y * kq.y + qt[0][kk].z * kq.z + qt[0][kk].w * kq.w;
                s1 += qt[1][kk].x * kq.x + qt[1][kk].y * kq.y + qt[1][kk].z * kq.z + qt[1][kk].w * kq.w;
                s2 += qt[2][kk].x * kq.x + qt[2][kk].y * kq.y + qt[2][kk].z * kq.z + qt[2][kk].w * kq.w;
                s3 += qt[3][kk].x * kq.x + qt[3][kk].y * kq.y + qt[3][kk].z * kq.z + qt[3][kk].w * kq.w;
            }
            // butterfly, DPP edition: lane ends with full score of head (lane&3)
            float a01 = (lane & 1) ? s1 : s0;
            float g01 = (lane & 1) ? s0 : s1;
            float a23 = (lane & 1) ? s3 : s2;
            float g23 = (lane & 1) ? s2 : s3;
            float u  = a01 + dppmov<0xB1>(g01);        // quad_perm xor1
            float v2 = a23 + dppmov<0xB1>(g23);
            float keep = (lane & 2) ? v2 : u;
            float give = (lane & 2) ? u : v2;
            float v = keep + dppmov<0x4E>(give);       // quad_perm xor2
            v += dppmov<0x124>(v);                     // row_ror:4
            v += dppmov<0x128>(v);                     // row_ror:8
            v += __int_as_float(__builtin_amdgcn_ds_swizzle(
                     __float_as_int(v), 0x401F));      // xor16 (within 32-half)
            v += __shfl_xor(v, 32, 64);                // cross-32
            unsigned char mk = (rr == 0) ? mb.x : (rr == 1) ? mb.y : (rr == 2) ? mb.z : mb.w;
            float p = __expf(mk ? -INFINITY : v);
            zacc += p;      // p is already the FULL row sum -> zacc is the
            ss[rr] = p;     // complete chunk-partial Z for head (lane&3).
            // broadcast (permuted) via quad_perm: pj = p of head (lane&3)^j
            float p1 = dppmov<0xB1>(p);
            float p2 = dppmov<0x4E>(p);
            float p3 = dppmov<0x4E>(p1);
#pragma unroll
            for (int kk = 0; kk < 4; kk++) {
                float4 kq = kv[cur][kk];
                acc[0][kk].x += p  * kq.x; acc[0][kk].y += p  * kq.y; acc[0][kk].z += p  * kq.z; acc[0][kk].w += p  * kq.w;
                acc[1][kk].x += p1 * kq.x; acc[1][kk].y += p1 * kq.y; acc[1][kk].z += p1 * kq.z; acc[1][kk].w += p1 * kq.w;
                acc[2][kk].x += p2 * kq.x; acc[2][kk].y += p2 * kq.y; acc[2][kk].z += p2 * kq.z; acc[2][kk].w += p2 * kq.w;
                acc[3][kk].x += p3 * kq.x; acc[3][kk].y += p3 * kq.y; acc[3][kk].z += p3 * kq.z; acc[3][kk].w += p3 * kq.w;
            }
        }
        if (lane < 4) {
            float4 o = make_float4(ss[0], ss[1], ss[2], ss[3]);
            *(float4*)&pout[((size_t)(hg * 4 + lane) * B + b) * L + l0 + rb * 4] = o;
        }
    }

    // phased LDS merge across chunks; un-permute head mapping h = hg*4+(hl^j)
    __syncthreads();
    for (int ph = 0; ph < 4; ph++) {
        if (chunk == ph) {
#pragma unroll
            for (int j = 0; j < 4; j++) {
                int h = hg * 4 + (hl ^ j);
                float* dst = &ctxl[(size_t)h * C + lane * 4];
                if (ph == 0) {
#pragma unroll
                    for (int kk = 0; kk < 4; kk++)
                        *(float4*)&dst[kk * 256] = acc[j][kk];
                } else {
#pragma unroll
                    for (int kk = 0; kk < 4; kk++) {
                        float4 o = *(const float4*)&dst[kk * 256];
                        float4 a = acc[j][kk];
                        o.x += a.x; o.y += a.y; o.z += a.z; o.w += a.w;
                        *(float4*)&dst[kk * 256] = o;
                    }
                }
            }
            if (lane < 4) {
                if (ph == 0) zl[hg * 4 + lane] = zacc;
                else         zl[hg * 4 + lane] += zacc;
            }
        }
        __syncthreads();
    }
    float* ap = accpart + ((size_t)b * 8 + lp) * (NH * C);
#pragma unroll
    for (int i = 0; i < 4; i++) {
        int idx = t * 16 + i * 4;
        *(float4*)&ap[idx] = *(const float4*)&ctxl[idx];
    }
    if (t < NH) zpart[((size_t)b * 8 + lp) * NH + t] = zl[t];
}

// ---------------------------------------------------------------------------
// k_combine2: ctx[b,n,c] = (sum_lp accpart) / Z; ALSO scales pout by Zinv.
__global__ void k_combine2(const float* __restrict__ accpart, const float* __restrict__ zpart,
                           float* __restrict__ ctx, float* __restrict__ pout) {
    int b = blockIdx.x, cq = blockIdx.y;
    int t = threadIdx.x;
    int c = cq * 256 + t;
    __shared__ float zi[NH];
    if (t < NH) {
        float z = 0.f;
#pragma unroll
        for (int lpp = 0; lpp < 8; lpp++) z += zpart[((size_t)b * 8 + lpp) * NH + t];
        zi[t] = 1.0f / z;
    }
    __syncthreads();
#pragma unroll
    for (int n = 0; n < NH; n++) {
        float s = 0.f;
#pragma unroll
        for (int lpp = 0; lpp < 8; lpp++)
            s += accpart[(((size_t)b * 8 + lpp) * NH + n) * C + c];
        ctx[((size_t)b * NH + n) * C + c] = s * zi[n];
    }
#pragma unroll
    for (int n = 0; n < NH; n++) {
        float zin = zi[n];
        float2* pp = (float2*)&pout[((size_t)n * B + b) * L + cq * 512];
        float2 v = pp[t];
        v.x *= zin; v.y *= zin;
        pp[t] = v;
    }
}

// ---------------------------------------------------------------------------
// k_out: output[b, j] = bv[j] + sum_c wv[j,c] * ctx[b, n(j), c]
__global__ void k_out(const float* __restrict__ ctx, const float* __restrict__ wv,
                      const float* __restrict__ bv, float* __restrict__ out) {
    int t = threadIdx.x, w = t >> 6, lane = t & 63;
    int j = blockIdx.x * 4 + w;
    int n = j >> 7;
    float4 W[4];
#pragma unroll
    for (int kk = 0; kk < 4; kk++)
        W[kk] = *(const float4*)&wv[(size_t)j * C + kk * 256 + lane * 4];
    float bj = bv[j];
    for (int b = 0; b < B; b++) {
        float s = 0.f;
#pragma unroll
        for (int kk = 0; kk < 4; kk++) {
            float4 cv = *(const float4*)&ctx[((size_t)b * NH + n) * C + kk * 256 + lane * 4];
            s += W[kk].x * cv.x + W[kk].y * cv.y + W[kk].z * cv.z + W[kk].w * cv.w;
        }
        s = wave_sum_dpp(s);
        if (lane == 63) out[(size_t)b * (NH * DK) + j] = s + bj;
    }
}

// ---------------------------------------------------------------------------
extern "C" void kernel_launch(void* const* d_in, const int* in_sizes, int n_in,
                              void* d_out, int out_size, void* d_ws, size_t ws_size,
                              hipStream_t stream) {
    const float* q    = (const float*)d_in[0];
    const float* kmat = (const float*)d_in[1];
    const unsigned char* mask = (const unsigned char*)d_in[2];
    const float* wq = (const float*)d_in[3];
    const float* bq = (const float*)d_in[4];
    const float* wk = (const float*)d_in[5];
    // d_in[6] = w_ks_b: softmax-invariant -> unused.
    const float* wv = (const float*)d_in[7];
    const float* bv = (const float*)d_in[8];

    float* out  = (float*)d_out;            // (64, 1024)
    float* attn = out + B * NH * DK;        // (8*64, 2048): exp(s) -> scaled

    float* ws      = (float*)d_ws;
    float* qs      = ws;                     // 65536 floats (dead after k_qtilde)
    float* zpart   = ws;                     // 4096 floats overlay (64*8*8)
    float* qtilde  = ws + 65536;             // 524288 floats, reused as ctx
    float* ctx     = qtilde;
    float* accpart = ws + 65536 + 524288;    // 64*8*8*1024 = 4194304 floats

    hipLaunchKernelGGL(k_qs, dim3(256), dim3(256), 0, stream, q, wq, bq, qs);
    hipLaunchKernelGGL(k_qtilde, dim3(32, 8), dim3(256), 0, stream, qs, wk, qtilde);
    hipLaunchKernelGGL(k_fused8b, dim3(64, 8), dim3(512), 0, stream,
                       kmat, qtilde, mask, attn, accpart, zpart);
    hipLaunchKernelGGL(k_combine2, dim3(64, 4), dim3(256), 0, stream,
                       accpart, zpart, ctx, attn);
    hipLaunchKernelGGL(k_out, dim3(256), dim3(256), 0, stream, ctx, wv, bv, out);
}

// Round 17
// 220.874 us; speedup vs baseline: 1.8877x; 1.0572x over previous
//
#include <hip/hip_runtime.h>
#include <hip/hip_bf16.h>
#include <math.h>

#define B 64
#define L 2048
#define C 1024          // D_K = D_Q
#define NH 8
#define DK 128
#define SCALE 0.08838834764831845f   // 1/sqrt(128)

// DPP helper: dst = dpp_perm(src) per CTRL; masked-off/invalid lanes yield 0.
template<int CTRL, int RMASK = 0xF>
__device__ __forceinline__ float dppmov(float x) {
    return __int_as_float(__builtin_amdgcn_update_dpp(
        0, __float_as_int(x), CTRL, RMASK, 0xF, true));
}
// Full wave64 sum via DPP; result in LANE 63.
__device__ __forceinline__ float wave_sum_dpp(float s) {
    s += dppmov<0x111>(s);          // row_shr:1
    s += dppmov<0x112>(s);          // row_shr:2
    s += dppmov<0x114>(s);          // row_shr:4
    s += dppmov<0x118>(s);          // row_shr:8
    s += dppmov<0x142, 0xa>(s);     // row_bcast:15 into rows 1,3
    s += dppmov<0x143, 0xc>(s);     // row_bcast:31 into rows 2,3 -> lane63 total
    return s;
}

// ---------------------------------------------------------------------------
// k_qs: qs[b, j] = bias[j] + sum_c q[b,c] * wq[j,c]   (64 x 1024)
__global__ void k_qs(const float* __restrict__ q, const float* __restrict__ wq,
                     const float* __restrict__ bq, float* __restrict__ qs) {
    int t = threadIdx.x, w = t >> 6, lane = t & 63;
    int j = blockIdx.x * 4 + w;
    float4 W[4];
#pragma unroll
    for (int kk = 0; kk < 4; kk++)
        W[kk] = *(const float4*)&wq[(size_t)j * C + kk * 256 + lane * 4];
    float bj = bq[j];
    for (int b = 0; b < B; b++) {
        float s = 0.f;
#pragma unroll
        for (int kk = 0; kk < 4; kk++) {
            float4 qv = *(const float4*)&q[(size_t)b * C + kk * 256 + lane * 4];
            s += W[kk].x * qv.x + W[kk].y * qv.y + W[kk].z * qv.z + W[kk].w * qv.w;
        }
        s = wave_sum_dpp(s);
        if (lane == 63) qs[(size_t)b * C + j] = s + bj;
    }
}

// ---------------------------------------------------------------------------
// k_qtilde: qtilde[b,n,c] = SCALE * sum_d qs[b, n*128+d] * wk[n*128+d, c]
__global__ void k_qtilde(const float* __restrict__ qs, const float* __restrict__ wk,
                         float* __restrict__ qtilde) {
    int n = blockIdx.x >> 2, cc = blockIdx.x & 3, bg = blockIdx.y;
    int t = threadIdx.x;
    int c = cc * 256 + t;
    __shared__ float qss[8][128];
    for (int p = 0; p < 4; p++) {
        int e = p * 256 + t;
        int i = e >> 7, d = e & 127;
        qss[i][d] = qs[(size_t)(bg * 8 + i) * C + n * DK + d];
    }
    __syncthreads();
    float acc[8];
#pragma unroll
    for (int i = 0; i < 8; i++) acc[i] = 0.f;
    for (int d = 0; d < DK; d += 4) {
        float wv0 = wk[(size_t)(n * DK + d + 0) * C + c];
        float wv1 = wk[(size_t)(n * DK + d + 1) * C + c];
        float wv2 = wk[(size_t)(n * DK + d + 2) * C + c];
        float wv3 = wk[(size_t)(n * DK + d + 3) * C + c];
#pragma unroll
        for (int i = 0; i < 8; i++) {
            acc[i] += qss[i][d + 0] * wv0 + qss[i][d + 1] * wv1
                    + qss[i][d + 2] * wv2 + qss[i][d + 3] * wv3;
        }
    }
#pragma unroll
    for (int i = 0; i < 8; i++)
        qtilde[((size_t)(bg * 8 + i) * NH + n) * C + c] = acc[i] * SCALE;
}

// ---------------------------------------------------------------------------
// k_fused11: round-13 fused8 with ONE change — the dist-1 prefetch is made
// UNCONDITIONAL via scalar clamp (rpre = min(r+1,127)). A conditional
// prefetch forces the compiler to merge paths with different outstanding
// VMEM counts -> vmcnt(0) drain at every use (pipeline defeated). The clamp
// gives a deterministic count -> counted vmcnt -> real overlap.
__global__ __launch_bounds__(512, 2) void k_fused11(
    const float* __restrict__ kmat, const float* __restrict__ qtilde,
    const unsigned char* __restrict__ mask,
    float* __restrict__ pout,             // (n*B + b)*L + l : exp(score)
    float* __restrict__ accpart,          // [b][lp4][n][C]
    float* __restrict__ zpart) {          // [b][lp4][n]
    const int b = blockIdx.x, lp = blockIdx.y;
    const int t = threadIdx.x, w = t >> 6, lane = t & 63;
    const int chunk = w >> 1;            // 0..3 (128 rows each)
    const int hg = w & 1;                // 0..1 (heads hg*4..hg*4+3)
    const int l0 = lp * 512 + chunk * 128;
    const int hl = lane & 3;

    __shared__ float ctxl[NH * C];       // 32 KB
    __shared__ float zl[NH];

    float4 qt[4][4];
#pragma unroll
    for (int j = 0; j < 4; j++)
#pragma unroll
        for (int kk = 0; kk < 4; kk++)
            qt[j][kk] = *(const float4*)&qtilde[((size_t)b * NH + hg * 4 + j) * C + kk * 256 + lane * 4];

    float4 acc[4][4];
#pragma unroll
    for (int j = 0; j < 4; j++)
#pragma unroll
        for (int kk = 0; kk < 4; kk++) acc[j][kk] = make_float4(0.f, 0.f, 0.f, 0.f);
    float zacc = 0.f;

    const float* kp = kmat + ((size_t)b * L + l0) * C + lane * 4;
    const unsigned char* mp = mask + (size_t)b * L + l0;

    float4 kv[2][4];
#pragma unroll
    for (int kk = 0; kk < 4; kk++) kv[0][kk] = *(const float4*)(kp + kk * 256);

    for (int rb = 0; rb < 32; rb++) {
        uchar4 mb = *(const uchar4*)&mp[rb * 4];
        float ss[4];
#pragma unroll
        for (int rr = 0; rr < 4; rr++) {
            const int r = rb * 4 + rr;
            const int cur = r & 1;
            // UNCONDITIONAL prefetch (scalar clamp): deterministic vmcnt.
            {
                const int rpre = (r < 127) ? (r + 1) : 127;
                const float* np = kp + (size_t)rpre * C;
#pragma unroll
                for (int kk = 0; kk < 4; kk++)
                    kv[cur ^ 1][kk] = *(const float4*)(np + kk * 256);
            }
            float s0 = 0.f, s1 = 0.f, s2 = 0.f, s3 = 0.f;
#pragma unroll
            for (int kk = 0; kk < 4; kk++) {
                float4 kq = kv[cur][kk];
                s0 += qt[0][kk].x * kq.x + qt[0][kk].y * kq.y + qt[0][kk].z * kq.z + qt[0][kk].w * kq.w;
                s1 += qt[1][kk].x * kq.x + qt[1][kk].y * kq.y + qt[1][kk].z * kq.z + qt[1][kk].w * kq.w;
                s2 += qt[2][kk].x * kq.x + qt[2][kk].y * kq.y + qt[2][kk].z * kq.z + qt[2][kk].w * kq.w;
                s3 += qt[3][kk].x * kq.x + qt[3][kk].y * kq.y + qt[3][kk].z * kq.z + qt[3][kk].w * kq.w;
            }
            // butterfly, DPP edition: lane ends with full score of head (lane&3)
            float a01 = (lane & 1) ? s1 : s0;
            float g01 = (lane & 1) ? s0 : s1;
            float a23 = (lane & 1) ? s3 : s2;
            float g23 = (lane & 1) ? s2 : s3;
            float u  = a01 + dppmov<0xB1>(g01);        // quad_perm xor1
            float v2 = a23 + dppmov<0xB1>(g23);
            float keep = (lane & 2) ? v2 : u;
            float give = (lane & 2) ? u : v2;
            float v = keep + dppmov<0x4E>(give);       // quad_perm xor2
            v += dppmov<0x124>(v);                     // row_ror:4
            v += dppmov<0x128>(v);                     // row_ror:8
            v += __int_as_float(__builtin_amdgcn_ds_swizzle(
                     __float_as_int(v), 0x401F));      // xor16 (within 32-half)
            v += __shfl_xor(v, 32, 64);                // cross-32
            unsigned char mk = (rr == 0) ? mb.x : (rr == 1) ? mb.y : (rr == 2) ? mb.z : mb.w;
            float p = __expf(mk ? -INFINITY : v);
            zacc += p;      // p is already the FULL row sum -> zacc is the
            ss[rr] = p;     // complete chunk-partial Z for head (lane&3).
            // broadcast (permuted) via quad_perm: pj = p of head (lane&3)^j
            float p1 = dppmov<0xB1>(p);
            float p2 = dppmov<0x4E>(p);
            float p3 = dppmov<0x4E>(p1);
#pragma unroll
            for (int kk = 0; kk < 4; kk++) {
                float4 kq = kv[cur][kk];
                acc[0][kk].x += p  * kq.x; acc[0][kk].y += p  * kq.y; acc[0][kk].z += p  * kq.z; acc[0][kk].w += p  * kq.w;
                acc[1][kk].x += p1 * kq.x; acc[1][kk].y += p1 * kq.y; acc[1][kk].z += p1 * kq.z; acc[1][kk].w += p1 * kq.w;
                acc[2][kk].x += p2 * kq.x; acc[2][kk].y += p2 * kq.y; acc[2][kk].z += p2 * kq.z; acc[2][kk].w += p2 * kq.w;
                acc[3][kk].x += p3 * kq.x; acc[3][kk].y += p3 * kq.y; acc[3][kk].z += p3 * kq.z; acc[3][kk].w += p3 * kq.w;
            }
        }
        if (lane < 4) {
            float4 o = make_float4(ss[0], ss[1], ss[2], ss[3]);
            *(float4*)&pout[((size_t)(hg * 4 + lane) * B + b) * L + l0 + rb * 4] = o;
        }
    }

    // phased LDS merge across chunks; un-permute head mapping h = hg*4+(hl^j)
    __syncthreads();
    for (int ph = 0; ph < 4; ph++) {
        if (chunk == ph) {
#pragma unroll
            for (int j = 0; j < 4; j++) {
                int h = hg * 4 + (hl ^ j);
                float* dst = &ctxl[(size_t)h * C + lane * 4];
                if (ph == 0) {
#pragma unroll
                    for (int kk = 0; kk < 4; kk++)
                        *(float4*)&dst[kk * 256] = acc[j][kk];
                } else {
#pragma unroll
                    for (int kk = 0; kk < 4; kk++) {
                        float4 o = *(const float4*)&dst[kk * 256];
                        float4 a = acc[j][kk];
                        o.x += a.x; o.y += a.y; o.z += a.z; o.w += a.w;
                        *(float4*)&dst[kk * 256] = o;
                    }
                }
            }
            if (lane < 4) {
                if (ph == 0) zl[hg * 4 + lane] = zacc;
                else         zl[hg * 4 + lane] += zacc;
            }
        }
        __syncthreads();
    }
    float* ap = accpart + ((size_t)b * 4 + lp) * (NH * C);
#pragma unroll
    for (int i = 0; i < 4; i++) {
        int idx = t * 16 + i * 4;
        *(float4*)&ap[idx] = *(const float4*)&ctxl[idx];
    }
    if (t < NH) zpart[((size_t)b * 4 + lp) * NH + t] = zl[t];
}

// ---------------------------------------------------------------------------
// k_combine2: ctx[b,n,c] = (sum_lp accpart) / Z; ALSO scales pout by Zinv.
__global__ void k_combine2(const float* __restrict__ accpart, const float* __restrict__ zpart,
                           float* __restrict__ ctx, float* __restrict__ pout) {
    int b = blockIdx.x, cq = blockIdx.y;
    int t = threadIdx.x;
    int c = cq * 256 + t;
    __shared__ float zi[NH];
    if (t < NH) {
        float z = 0.f;
#pragma unroll
        for (int lpp = 0; lpp < 4; lpp++) z += zpart[((size_t)b * 4 + lpp) * NH + t];
        zi[t] = 1.0f / z;
    }
    __syncthreads();
#pragma unroll
    for (int n = 0; n < NH; n++) {
        float s = 0.f;
#pragma unroll
        for (int lpp = 0; lpp < 4; lpp++)
            s += accpart[(((size_t)b * 4 + lpp) * NH + n) * C + c];
        ctx[((size_t)b * NH + n) * C + c] = s * zi[n];
    }
#pragma unroll
    for (int n = 0; n < NH; n++) {
        float zin = zi[n];
        float2* pp = (float2*)&pout[((size_t)n * B + b) * L + cq * 512];
        float2 v = pp[t];
        v.x *= zin; v.y *= zin;
        pp[t] = v;
    }
}

// ---------------------------------------------------------------------------
// k_out: output[b, j] = bv[j] + sum_c wv[j,c] * ctx[b, n(j), c]
__global__ void k_out(const float* __restrict__ ctx, const float* __restrict__ wv,
                      const float* __restrict__ bv, float* __restrict__ out) {
    int t = threadIdx.x, w = t >> 6, lane = t & 63;
    int j = blockIdx.x * 4 + w;
    int n = j >> 7;
    float4 W[4];
#pragma unroll
    for (int kk = 0; kk < 4; kk++)
        W[kk] = *(const float4*)&wv[(size_t)j * C + kk * 256 + lane * 4];
    float bj = bv[j];
    for (int b = 0; b < B; b++) {
        float s = 0.f;
#pragma unroll
        for (int kk = 0; kk < 4; kk++) {
            float4 cv = *(const float4*)&ctx[((size_t)b * NH + n) * C + kk * 256 + lane * 4];
            s += W[kk].x * cv.x + W[kk].y * cv.y + W[kk].z * cv.z + W[kk].w * cv.w;
        }
        s = wave_sum_dpp(s);
        if (lane == 63) out[(size_t)b * (NH * DK) + j] = s + bj;
    }
}

// ---------------------------------------------------------------------------
extern "C" void kernel_launch(void* const* d_in, const int* in_sizes, int n_in,
                              void* d_out, int out_size, void* d_ws, size_t ws_size,
                              hipStream_t stream) {
    const float* q    = (const float*)d_in[0];
    const float* kmat = (const float*)d_in[1];
    const unsigned char* mask = (const unsigned char*)d_in[2];
    const float* wq = (const float*)d_in[3];
    const float* bq = (const float*)d_in[4];
    const float* wk = (const float*)d_in[5];
    // d_in[6] = w_ks_b: softmax-invariant -> unused.
    const float* wv = (const float*)d_in[7];
    const float* bv = (const float*)d_in[8];

    float* out  = (float*)d_out;            // (64, 1024)
    float* attn = out + B * NH * DK;        // (8*64, 2048): exp(s) -> scaled

    float* ws      = (float*)d_ws;
    float* qs      = ws;                     // 65536 floats (dead after k_qtilde)
    float* zpart   = ws;                     // 2048 floats overlay (64*4*8)
    float* qtilde  = ws + 65536;             // 524288 floats, reused as ctx
    float* ctx     = qtilde;
    float* accpart = ws + 65536 + 524288;    // 2097152 floats

    hipLaunchKernelGGL(k_qs, dim3(256), dim3(256), 0, stream, q, wq, bq, qs);
    hipLaunchKernelGGL(k_qtilde, dim3(32, 8), dim3(256), 0, stream, qs, wk, qtilde);
    hipLaunchKernelGGL(k_fused11, dim3(64, 4), dim3(512), 0, stream,
                       kmat, qtilde, mask, attn, accpart, zpart);
    hipLaunchKernelGGL(k_combine2, dim3(64, 4), dim3(256), 0, stream,
                       accpart, zpart, ctx, attn);
    hipLaunchKernelGGL(k_out, dim3(256), dim3(256), 0, stream, ctx, wv, bv, out);
}